// Round 1
// baseline (273.964 us; speedup 1.0000x reference)
//
#include <hip/hip_runtime.h>

#define NROWS 2097152
#define W 16

__global__ __launch_bounds__(256) void cel_weight_kernel(
    const float* __restrict__ predict,
    const float* __restrict__ target,
    const float* __restrict__ penalty,
    float* __restrict__ out)
{
    __shared__ float s_pen[W * W];
    __shared__ float s_part[4];

    const int tid = threadIdx.x;
    if (tid < W * W) s_pen[tid] = penalty[tid];
    __syncthreads();

    float acc = 0.0f;
    const int stride = gridDim.x * blockDim.x;

    for (int r = blockIdx.x * blockDim.x + tid; r < NROWS; r += stride) {
        const float4* prow = (const float4*)(predict + (size_t)r * W);
        const float4* trow = (const float4*)(target + (size_t)r * W);
        // Issue all 8 vector loads before any compute (latency overlap).
        float4 p0 = prow[0], p1 = prow[1], p2 = prow[2], p3 = prow[3];
        float4 t0 = trow[0], t1 = trow[1], t2 = trow[2], t3 = trow[3];

        float pv[W] = {p0.x, p0.y, p0.z, p0.w, p1.x, p1.y, p1.z, p1.w,
                       p2.x, p2.y, p2.z, p2.w, p3.x, p3.y, p3.z, p3.w};
        float tv[W] = {t0.x, t0.y, t0.z, t0.w, t1.x, t1.y, t1.z, t1.w,
                       t2.x, t2.y, t2.z, t2.w, t3.x, t3.y, t3.z, t3.w};

        // argmax(predict) with first-index tie-break (matches jnp.argmax)
        float pmax = pv[0]; int pidx = 0;
        #pragma unroll
        for (int j = 1; j < W; ++j) {
            if (pv[j] > pmax) { pmax = pv[j]; pidx = j; }
        }
        // softmax denominator; numerator at argmax is exp(0)=1
        float s = 0.0f;
        #pragma unroll
        for (int j = 0; j < W; ++j) s += __expf(pv[j] - pmax);

        // argmax(target)
        float tmax = tv[0]; int tidx = 0;
        #pragma unroll
        for (int j = 1; j < W; ++j) {
            if (tv[j] > tmax) { tmax = tv[j]; tidx = j; }
        }

        float wgt = (pidx == tidx) ? 0.0f : s_pen[tidx * W + pidx];
        acc += wgt / s;
    }

    // wave-64 reduction
    #pragma unroll
    for (int off = 32; off > 0; off >>= 1)
        acc += __shfl_down(acc, off);

    const int lane = tid & 63;
    const int wid  = tid >> 6;
    if (lane == 0) s_part[wid] = acc;
    __syncthreads();

    if (tid == 0) {
        float tot = s_part[0] + s_part[1] + s_part[2] + s_part[3];
        atomicAdd(out, tot * (1.0f / (float)NROWS));
    }
}

extern "C" void kernel_launch(void* const* d_in, const int* in_sizes, int n_in,
                              void* d_out, int out_size, void* d_ws, size_t ws_size,
                              hipStream_t stream)
{
    const float* predict = (const float*)d_in[0];
    const float* target  = (const float*)d_in[1];
    const float* penalty = (const float*)d_in[2];
    float* out = (float*)d_out;

    // d_out is poisoned (0xAA) before every replay — zero it on-stream.
    hipMemsetAsync(out, 0, sizeof(float) * out_size, stream);

    dim3 grid(2048), block(256);
    cel_weight_kernel<<<grid, block, 0, stream>>>(predict, target, penalty, out);
}